// Round 4
// baseline (138.909 us; speedup 1.0000x reference)
//
#include <hip/hip_runtime.h>

// YOLOv1 loss, fused single-pass kernel.
// Round-3 lesson: scattered-load kernel was LATENCY-bound (8 loads in flight/wave,
// VALUBusy 8%). Fix: 2 cells per lane = one 240B-aligned chunk = 29 independent
// float4 loads per thread issued up front (max MLP), all bytes consumed exactly
// once, no LDS staging, no atomics (per-block partials + final reduce kernel).

constexpr int SS = 14;

__device__ __forceinline__ void box_loss(
    float p0, float p1, float p2, float p3, float p4,
    float p5, float p6, float p7, float p8, float p9,
    float t0, float t1, float t2, float t3, float t4,
    float offx, float offy,
    float& s0, float& s1, float& s2, float& s3, float& m_out)
{
    float m  = (t4 == 1.0f) ? 1.0f : 0.0f;
    float nm = (t4 == 0.0f) ? 1.0f : 0.0f;
    m_out = m;

    const float S = 14.0f;
    float tcx = t0 / S + offx / S;
    float tcy = t1 / S + offy / S;
    float thw = 0.5f * t2, thh = 0.5f * t3;
    float tx0 = tcx - thw, ty0 = tcy - thh;
    float tx1 = tcx + thw, ty1 = tcy + thh;
    float area_t = t2 * t3;

    float iou0, iou1;
    {
        float cx = p0 / S + offx / S, cy = p1 / S + offy / S;
        float hw = 0.5f * p2, hh = 0.5f * p3;
        float x0 = cx - hw, y0 = cy - hh, x1 = cx + hw, y1 = cy + hh;
        float wx = fmaxf(fminf(tx1, x1) - fmaxf(tx0, x0), 0.f);
        float wy = fmaxf(fminf(ty1, y1) - fmaxf(ty0, y0), 0.f);
        float inter = wx * wy;
        iou0 = inter / (area_t + p2 * p3 - inter);
    }
    {
        float cx = p5 / S + offx / S, cy = p6 / S + offy / S;
        float hw = 0.5f * p7, hh = 0.5f * p8;
        float x0 = cx - hw, y0 = cy - hh, x1 = cx + hw, y1 = cy + hh;
        float wx = fmaxf(fminf(tx1, x1) - fmaxf(tx0, x0), 0.f);
        float wy = fmaxf(fminf(ty1, y1) - fmaxf(ty0, y0), 0.f);
        float inter = wx * wy;
        iou1 = inter / (area_t + p7 * p8 - inter);
    }

    int k = (iou1 > iou0) ? 1 : 0;     // jnp.argmax first-max tie-break
    float b0 = k ? p5 : p0, b1 = k ? p6 : p1;
    float b2 = k ? p7 : p2, b3 = k ? p8 : p3, b4 = k ? p9 : p4;
    float biou = k ? iou1 : iou0;

    float d0 = t0 - b0, d1 = t1 - b1;
    s0 += m * (d0 * d0 + d1 * d1);

    float e0 = sqrtf(t2) - sqrtf(b2);
    float e1 = sqrtf(t3) - sqrtf(b3);
    s1 += m * (e0 * e0 + e1 * e1);

    float dc = biou - b4;
    s2 += m * dc * dc;

    float conf_other = k ? p4 : p9;
    s3 += nm * (p4 * p4 + p9 * p9) + m * conf_other * conf_other;
}

__global__ __launch_bounds__(256) void yolo_fused(
    const float* __restrict__ pred,
    const float* __restrict__ targ,
    float4* __restrict__ partA,   // per-block {xy, wh, Cobj, Cnoobj}
    float*  __restrict__ partB)   // per-block cls
{
    const int pair = blockIdx.x * 256 + threadIdx.x;   // grid sized exactly
    const float4* P = reinterpret_cast<const float4*>(pred) + (size_t)pair * 15;
    const float4* T = reinterpret_cast<const float4*>(targ) + (size_t)pair * 15;

    // issue all loads up front (independent -> deep MLP)
    float4 pf0 = P[0],  pf1 = P[1],  pf2 = P[2],  pf3 = P[3],  pf4 = P[4];
    float4 pf5 = P[5],  pf6 = P[6],  pf7 = P[7],  pf8 = P[8],  pf9 = P[9];
    float4 pf10 = P[10], pf11 = P[11], pf12 = P[12], pf13 = P[13], pf14 = P[14];
    float4 tf0 = T[0],  tf1 = T[1],  tf2 = T[2],  tf3 = T[3],  tf4 = T[4];
    float4 tf5 = T[5],  tf6 = T[6],  tf7 = T[7],  tf8 = T[8];      // T[9]=elems36..39 unused
    float4 tf10 = T[10], tf11 = T[11], tf12 = T[12], tf13 = T[13], tf14 = T[14];

    // cell0 = 2*pair (even) -> ij even -> ij%14 <= 12 -> cell1 same row, offx+1
    int ij = (2 * pair) % (SS * SS);
    float offx0 = (float)(ij % SS);
    float offy0 = (float)(ij / SS);

    float s0 = 0.f, s1 = 0.f, s2 = 0.f, s3 = 0.f, m0, m1;

    // cell0: pred elems 0..9, targ elems 0..4
    box_loss(pf0.x, pf0.y, pf0.z, pf0.w, pf1.x, pf1.y, pf1.z, pf1.w, pf2.x, pf2.y,
             tf0.x, tf0.y, tf0.z, tf0.w, tf1.x,
             offx0, offy0, s0, s1, s2, s3, m0);
    // cell1: pred elems 30..39, targ elems 30..34
    box_loss(pf7.z, pf7.w, pf8.x, pf8.y, pf8.z, pf8.w, pf9.x, pf9.y, pf9.z, pf9.w,
             tf7.z, tf7.w, tf8.x, tf8.y, tf8.z,
             offx0 + 1.0f, offy0, s0, s1, s2, s3, m1);

    // class loss: cell0 elems 10..29, cell1 elems 40..59
    float c0 = 0.f, c1 = 0.f, d;
    d = tf2.z - pf2.z; c0 += d * d;   d = tf2.w - pf2.w; c0 += d * d;
    d = tf3.x - pf3.x; c0 += d * d;   d = tf3.y - pf3.y; c0 += d * d;
    d = tf3.z - pf3.z; c0 += d * d;   d = tf3.w - pf3.w; c0 += d * d;
    d = tf4.x - pf4.x; c0 += d * d;   d = tf4.y - pf4.y; c0 += d * d;
    d = tf4.z - pf4.z; c0 += d * d;   d = tf4.w - pf4.w; c0 += d * d;
    d = tf5.x - pf5.x; c0 += d * d;   d = tf5.y - pf5.y; c0 += d * d;
    d = tf5.z - pf5.z; c0 += d * d;   d = tf5.w - pf5.w; c0 += d * d;
    d = tf6.x - pf6.x; c0 += d * d;   d = tf6.y - pf6.y; c0 += d * d;
    d = tf6.z - pf6.z; c0 += d * d;   d = tf6.w - pf6.w; c0 += d * d;
    d = tf7.x - pf7.x; c0 += d * d;   d = tf7.y - pf7.y; c0 += d * d;

    d = tf10.x - pf10.x; c1 += d * d; d = tf10.y - pf10.y; c1 += d * d;
    d = tf10.z - pf10.z; c1 += d * d; d = tf10.w - pf10.w; c1 += d * d;
    d = tf11.x - pf11.x; c1 += d * d; d = tf11.y - pf11.y; c1 += d * d;
    d = tf11.z - pf11.z; c1 += d * d; d = tf11.w - pf11.w; c1 += d * d;
    d = tf12.x - pf12.x; c1 += d * d; d = tf12.y - pf12.y; c1 += d * d;
    d = tf12.z - pf12.z; c1 += d * d; d = tf12.w - pf12.w; c1 += d * d;
    d = tf13.x - pf13.x; c1 += d * d; d = tf13.y - pf13.y; c1 += d * d;
    d = tf13.z - pf13.z; c1 += d * d; d = tf13.w - pf13.w; c1 += d * d;
    d = tf14.x - pf14.x; c1 += d * d; d = tf14.y - pf14.y; c1 += d * d;
    d = tf14.z - pf14.z; c1 += d * d; d = tf14.w - pf14.w; c1 += d * d;

    float s4 = m0 * c0 + m1 * c1;

    // wave butterfly reduce
#pragma unroll
    for (int o = 32; o > 0; o >>= 1) {
        s0 += __shfl_down(s0, o);
        s1 += __shfl_down(s1, o);
        s2 += __shfl_down(s2, o);
        s3 += __shfl_down(s3, o);
        s4 += __shfl_down(s4, o);
    }

    __shared__ float red[4][5];
    int wave = threadIdx.x >> 6;
    if ((threadIdx.x & 63) == 0) {
        red[wave][0] = s0; red[wave][1] = s1; red[wave][2] = s2;
        red[wave][3] = s3; red[wave][4] = s4;
    }
    __syncthreads();
    if (threadIdx.x == 0) {
        partA[blockIdx.x] = make_float4(
            red[0][0] + red[1][0] + red[2][0] + red[3][0],
            red[0][1] + red[1][1] + red[2][1] + red[3][1],
            red[0][2] + red[1][2] + red[2][2] + red[3][2],
            red[0][3] + red[1][3] + red[2][3] + red[3][3]);
        partB[blockIdx.x] =
            red[0][4] + red[1][4] + red[2][4] + red[3][4];
    }
}

__global__ __launch_bounds__(256) void yolo_final(
    const float4* __restrict__ partA, int nA,
    const float* __restrict__ partB,
    float* __restrict__ out, float invN)
{
    float a0 = 0.f, a1 = 0.f, a2 = 0.f, a3 = 0.f, b = 0.f;
    for (int i = threadIdx.x; i < nA; i += 256) {
        float4 v = partA[i];
        a0 += v.x; a1 += v.y; a2 += v.z; a3 += v.w;
        b += partB[i];
    }
#pragma unroll
    for (int o = 32; o > 0; o >>= 1) {
        a0 += __shfl_down(a0, o);
        a1 += __shfl_down(a1, o);
        a2 += __shfl_down(a2, o);
        a3 += __shfl_down(a3, o);
        b  += __shfl_down(b, o);
    }
    __shared__ float red[4][5];
    int wave = threadIdx.x >> 6;
    if ((threadIdx.x & 63) == 0) {
        red[wave][0] = a0; red[wave][1] = a1; red[wave][2] = a2;
        red[wave][3] = a3; red[wave][4] = b;
    }
    __syncthreads();
    if (threadIdx.x == 0) {
        float xy     = (red[0][0]+red[1][0]+red[2][0]+red[3][0]) * 5.0f * invN;
        float wh     = (red[0][1]+red[1][1]+red[2][1]+red[3][1]) * 5.0f * invN;
        float cobj   = (red[0][2]+red[1][2]+red[2][2]+red[3][2]) * invN;
        float cnoobj = (red[0][3]+red[1][3]+red[2][3]+red[3][3]) * 0.5f * invN;
        float cls    = (red[0][4]+red[1][4]+red[2][4]+red[3][4]) * invN;
        out[0] = xy + wh + cobj + cnoobj + cls;
        out[1] = xy;
        out[2] = wh;
        out[3] = cobj;
        out[4] = cnoobj;
        out[5] = cls;
    }
}

extern "C" void kernel_launch(void* const* d_in, const int* in_sizes, int n_in,
                              void* d_out, int out_size, void* d_ws, size_t ws_size,
                              hipStream_t stream)
{
    const float* pred = (const float*)d_in[0];
    const float* targ = (const float*)d_in[1];
    int ncells = in_sizes[0] / 30;             // 802816
    int npairs = ncells / 2;                   // 401408
    int blocks = npairs / 256;                 // 1568 exact
    int N      = ncells / (SS * SS);

    float4* partA = (float4*)d_ws;
    float*  partB = (float*)((char*)d_ws + (size_t)blocks * sizeof(float4));

    yolo_fused<<<blocks, 256, 0, stream>>>(pred, targ, partA, partB);
    yolo_final<<<1, 256, 0, stream>>>(partA, blocks, partB,
                                      (float*)d_out, 1.0f / (float)N);
}

// Round 5
// 60.261 us; speedup vs baseline: 2.3051x; 2.3051x over previous
//
#include <hip/hip_runtime.h>

// YOLOv1 loss, fused, fully-coalesced single pass.
// Round-4 lesson: per-lane-contiguous (240B/lane) loads over-fetched HBM 2.37x
// (same line needed by ~8 different load instrs; no merge under deep MLP).
// This version: lane i always reads consecutive 16B (wave = 1024B contiguous),
// box subset staged to LDS (AoS stride 15, odd -> conflict-free), class summed
// per-cell via LDS float atomics, mask applied in phase 2. No global atomics.

constexpr int SS  = 14;
constexpr int TPB = 256;
constexpr int CPB = 512;              // cells per block
constexpr int K   = CPB * 30 / 4 / TPB;   // 15 float4 per thread per tensor

__device__ __forceinline__ void box_loss(
    float p0, float p1, float p2, float p3, float p4,
    float p5, float p6, float p7, float p8, float p9,
    float t0, float t1, float t2, float t3, float t4,
    float offx, float offy,
    float& s0, float& s1, float& s2, float& s3, float& m_out)
{
    float m  = (t4 == 1.0f) ? 1.0f : 0.0f;
    float nm = (t4 == 0.0f) ? 1.0f : 0.0f;
    m_out = m;

    const float S = 14.0f;
    float tcx = t0 / S + offx / S;
    float tcy = t1 / S + offy / S;
    float thw = 0.5f * t2, thh = 0.5f * t3;
    float tx0 = tcx - thw, ty0 = tcy - thh;
    float tx1 = tcx + thw, ty1 = tcy + thh;
    float area_t = t2 * t3;

    float iou0, iou1;
    {
        float cx = p0 / S + offx / S, cy = p1 / S + offy / S;
        float hw = 0.5f * p2, hh = 0.5f * p3;
        float x0 = cx - hw, y0 = cy - hh, x1 = cx + hw, y1 = cy + hh;
        float wx = fmaxf(fminf(tx1, x1) - fmaxf(tx0, x0), 0.f);
        float wy = fmaxf(fminf(ty1, y1) - fmaxf(ty0, y0), 0.f);
        float inter = wx * wy;
        iou0 = inter / (area_t + p2 * p3 - inter);
    }
    {
        float cx = p5 / S + offx / S, cy = p6 / S + offy / S;
        float hw = 0.5f * p7, hh = 0.5f * p8;
        float x0 = cx - hw, y0 = cy - hh, x1 = cx + hw, y1 = cy + hh;
        float wx = fmaxf(fminf(tx1, x1) - fmaxf(tx0, x0), 0.f);
        float wy = fmaxf(fminf(ty1, y1) - fmaxf(ty0, y0), 0.f);
        float inter = wx * wy;
        iou1 = inter / (area_t + p7 * p8 - inter);
    }

    int k = (iou1 > iou0) ? 1 : 0;     // jnp.argmax first-max tie-break
    float b0 = k ? p5 : p0, b1 = k ? p6 : p1;
    float b2 = k ? p7 : p2, b3 = k ? p8 : p3, b4 = k ? p9 : p4;
    float biou = k ? iou1 : iou0;

    float d0 = t0 - b0, d1 = t1 - b1;
    s0 += m * (d0 * d0 + d1 * d1);

    float e0 = sqrtf(t2) - sqrtf(b2);
    float e1 = sqrtf(t3) - sqrtf(b3);
    s1 += m * (e0 * e0 + e1 * e1);

    float dc = biou - b4;
    s2 += m * dc * dc;

    float conf_other = k ? p4 : p9;
    s3 += nm * (p4 * p4 + p9 * p9) + m * conf_other * conf_other;
}

__global__ __launch_bounds__(TPB) void yolo_fused(
    const float* __restrict__ pred,
    const float* __restrict__ targ,
    float4* __restrict__ partA,   // per-block {xy, wh, Cobj, Cnoobj}
    float*  __restrict__ partB)   // per-block cls
{
    __shared__ float Lbox[CPB * 15];   // rows 0..9 pred box, 10..14 targ box (14 = t4)
    __shared__ float Lcls[CPB];        // unmasked per-cell class sum

    const int tid = threadIdx.x;
    const size_t blk4 = (size_t)blockIdx.x * (CPB * 30 / 4);
    const float4* P = reinterpret_cast<const float4*>(pred) + blk4;
    const float4* T = reinterpret_cast<const float4*>(targ) + blk4;

    Lcls[tid] = 0.f;
    Lcls[tid + 256] = 0.f;
    __syncthreads();

    // coalesced loads: lane i -> consecutive 16B. Issue all up front (MLP).
    float4 pv[K], tv[K];
#pragma unroll
    for (int k = 0; k < K; ++k) {
        pv[k] = P[k * TPB + tid];
        tv[k] = T[k * TPB + tid];
    }

#pragma unroll
    for (int k = 0; k < K; ++k) {
        unsigned l    = 4u * (unsigned)(k * TPB + tid);  // block-local float idx
        unsigned cell = l / 30u;
        unsigned e    = l - 30u * cell;                  // even, 0..28
        float pc[4] = { pv[k].x, pv[k].y, pv[k].z, pv[k].w };
        float tc[4] = { tv[k].x, tv[k].y, tv[k].z, tv[k].w };
        float clsum = 0.f;
#pragma unroll
        for (int j = 0; j < 4; ++j) {
            unsigned ej = e + j, c2 = cell;
            if (ej >= 30u) { ej -= 30u; c2 += 1u; }      // only e==28, j>=2
            if (ej < 10u) Lbox[c2 * 15u + ej] = pc[j];
            if (ej < 5u)  Lbox[c2 * 15u + 10u + ej] = tc[j];
            if (ej >= 10u) { float d = tc[j] - pc[j]; clsum += d * d; }
        }
        if (e >= 8u) atomicAdd(&Lcls[cell], clsum);      // class never wraps
    }
    __syncthreads();

    // phase 2: 2 cells per thread from LDS (stride 15 -> conflict-free)
    float s0 = 0.f, s1 = 0.f, s2 = 0.f, s3 = 0.f, s4 = 0.f;
#pragma unroll
    for (int h = 0; h < 2; ++h) {
        int c = tid + h * 256;
        const float* Bx = &Lbox[c * 15];
        float p0 = Bx[0], p1 = Bx[1], p2 = Bx[2], p3 = Bx[3], p4 = Bx[4];
        float p5 = Bx[5], p6 = Bx[6], p7 = Bx[7], p8 = Bx[8], p9 = Bx[9];
        float t0 = Bx[10], t1 = Bx[11], t2 = Bx[12], t3 = Bx[13], t4 = Bx[14];

        unsigned gcell = (unsigned)blockIdx.x * CPB + (unsigned)c;
        unsigned ij = gcell % 196u;
        float offx = (float)(ij % 14u);   // off = (j, i): x = column
        float offy = (float)(ij / 14u);

        float m;
        box_loss(p0, p1, p2, p3, p4, p5, p6, p7, p8, p9,
                 t0, t1, t2, t3, t4, offx, offy, s0, s1, s2, s3, m);
        s4 += m * Lcls[c];
    }

    // wave butterfly reduce
#pragma unroll
    for (int o = 32; o > 0; o >>= 1) {
        s0 += __shfl_down(s0, o);
        s1 += __shfl_down(s1, o);
        s2 += __shfl_down(s2, o);
        s3 += __shfl_down(s3, o);
        s4 += __shfl_down(s4, o);
    }

    __shared__ float red[4][5];
    int wave = tid >> 6;
    if ((tid & 63) == 0) {
        red[wave][0] = s0; red[wave][1] = s1; red[wave][2] = s2;
        red[wave][3] = s3; red[wave][4] = s4;
    }
    __syncthreads();
    if (tid == 0) {
        partA[blockIdx.x] = make_float4(
            red[0][0] + red[1][0] + red[2][0] + red[3][0],
            red[0][1] + red[1][1] + red[2][1] + red[3][1],
            red[0][2] + red[1][2] + red[2][2] + red[3][2],
            red[0][3] + red[1][3] + red[2][3] + red[3][3]);
        partB[blockIdx.x] =
            red[0][4] + red[1][4] + red[2][4] + red[3][4];
    }
}

__global__ __launch_bounds__(256) void yolo_final(
    const float4* __restrict__ partA, int nA,
    const float* __restrict__ partB,
    float* __restrict__ out, float invN)
{
    float a0 = 0.f, a1 = 0.f, a2 = 0.f, a3 = 0.f, b = 0.f;
    for (int i = threadIdx.x; i < nA; i += 256) {
        float4 v = partA[i];
        a0 += v.x; a1 += v.y; a2 += v.z; a3 += v.w;
        b += partB[i];
    }
#pragma unroll
    for (int o = 32; o > 0; o >>= 1) {
        a0 += __shfl_down(a0, o);
        a1 += __shfl_down(a1, o);
        a2 += __shfl_down(a2, o);
        a3 += __shfl_down(a3, o);
        b  += __shfl_down(b, o);
    }
    __shared__ float red[4][5];
    int wave = threadIdx.x >> 6;
    if ((threadIdx.x & 63) == 0) {
        red[wave][0] = a0; red[wave][1] = a1; red[wave][2] = a2;
        red[wave][3] = a3; red[wave][4] = b;
    }
    __syncthreads();
    if (threadIdx.x == 0) {
        float xy     = (red[0][0]+red[1][0]+red[2][0]+red[3][0]) * 5.0f * invN;
        float wh     = (red[0][1]+red[1][1]+red[2][1]+red[3][1]) * 5.0f * invN;
        float cobj   = (red[0][2]+red[1][2]+red[2][2]+red[3][2]) * invN;
        float cnoobj = (red[0][3]+red[1][3]+red[2][3]+red[3][3]) * 0.5f * invN;
        float cls    = (red[0][4]+red[1][4]+red[2][4]+red[3][4]) * invN;
        out[0] = xy + wh + cobj + cnoobj + cls;
        out[1] = xy;
        out[2] = wh;
        out[3] = cobj;
        out[4] = cnoobj;
        out[5] = cls;
    }
}

extern "C" void kernel_launch(void* const* d_in, const int* in_sizes, int n_in,
                              void* d_out, int out_size, void* d_ws, size_t ws_size,
                              hipStream_t stream)
{
    const float* pred = (const float*)d_in[0];
    const float* targ = (const float*)d_in[1];
    int ncells = in_sizes[0] / 30;             // 802816
    int blocks = ncells / CPB;                 // 1568 exact
    int N      = ncells / (SS * SS);

    float4* partA = (float4*)d_ws;
    float*  partB = (float*)((char*)d_ws + (size_t)blocks * sizeof(float4));

    yolo_fused<<<blocks, TPB, 0, stream>>>(pred, targ, partA, partB);
    yolo_final<<<1, 256, 0, stream>>>(partA, blocks, partB,
                                      (float*)d_out, 1.0f / (float)N);
}

// Round 6
// 56.195 us; speedup vs baseline: 2.4719x; 1.0723x over previous
//
#include <hip/hip_runtime.h>

// YOLOv1 loss, fused, fully-coalesced, occupancy-tuned.
// Round-5 lesson: correct FETCH (compulsory-only) but 23% occupancy (33KB LDS)
// left the stream latency-bound at ~3.3 TB/s effective. This version halves the
// LDS tile (256 cells = 16.4KB) and runs 2 tiles per block sequentially, so
// ~7 blocks/CU (~28 waves) keep enough loads in flight to reach streaming BW.

constexpr int SS  = 14;
constexpr int TPB = 256;
constexpr int CPT = 256;             // cells per tile
constexpr int NCH = CPT * 30 / 4;    // 1920 float4 chunks per tensor per tile

__device__ __forceinline__ void box_loss(
    float p0, float p1, float p2, float p3, float p4,
    float p5, float p6, float p7, float p8, float p9,
    float t0, float t1, float t2, float t3, float t4,
    float offx, float offy,
    float& s0, float& s1, float& s2, float& s3, float& m_out)
{
    float m  = (t4 == 1.0f) ? 1.0f : 0.0f;
    float nm = (t4 == 0.0f) ? 1.0f : 0.0f;
    m_out = m;

    const float S = 14.0f;
    float tcx = t0 / S + offx / S;
    float tcy = t1 / S + offy / S;
    float thw = 0.5f * t2, thh = 0.5f * t3;
    float tx0 = tcx - thw, ty0 = tcy - thh;
    float tx1 = tcx + thw, ty1 = tcy + thh;
    float area_t = t2 * t3;

    float iou0, iou1;
    {
        float cx = p0 / S + offx / S, cy = p1 / S + offy / S;
        float hw = 0.5f * p2, hh = 0.5f * p3;
        float x0 = cx - hw, y0 = cy - hh, x1 = cx + hw, y1 = cy + hh;
        float wx = fmaxf(fminf(tx1, x1) - fmaxf(tx0, x0), 0.f);
        float wy = fmaxf(fminf(ty1, y1) - fmaxf(ty0, y0), 0.f);
        float inter = wx * wy;
        iou0 = inter / (area_t + p2 * p3 - inter);
    }
    {
        float cx = p5 / S + offx / S, cy = p6 / S + offy / S;
        float hw = 0.5f * p7, hh = 0.5f * p8;
        float x0 = cx - hw, y0 = cy - hh, x1 = cx + hw, y1 = cy + hh;
        float wx = fmaxf(fminf(tx1, x1) - fmaxf(tx0, x0), 0.f);
        float wy = fmaxf(fminf(ty1, y1) - fmaxf(ty0, y0), 0.f);
        float inter = wx * wy;
        iou1 = inter / (area_t + p7 * p8 - inter);
    }

    int k = (iou1 > iou0) ? 1 : 0;     // jnp.argmax first-max tie-break
    float b0 = k ? p5 : p0, b1 = k ? p6 : p1;
    float b2 = k ? p7 : p2, b3 = k ? p8 : p3, b4 = k ? p9 : p4;
    float biou = k ? iou1 : iou0;

    float d0 = t0 - b0, d1 = t1 - b1;
    s0 += m * (d0 * d0 + d1 * d1);

    float e0 = sqrtf(t2) - sqrtf(b2);
    float e1 = sqrtf(t3) - sqrtf(b3);
    s1 += m * (e0 * e0 + e1 * e1);

    float dc = biou - b4;
    s2 += m * dc * dc;

    float conf_other = k ? p4 : p9;
    s3 += nm * (p4 * p4 + p9 * p9) + m * conf_other * conf_other;
}

__global__ __launch_bounds__(TPB) void yolo_fused(
    const float* __restrict__ pred,
    const float* __restrict__ targ,
    float4* __restrict__ partA,   // per-block {xy, wh, Cobj, Cnoobj}
    float*  __restrict__ partB)   // per-block cls
{
    __shared__ float Lbox[CPT * 15];   // rows 0..9 pred box, 10..14 targ box (14 = t4)
    __shared__ float Lcls[CPT];        // unmasked per-cell class sum

    const int tid = threadIdx.x;
    float s0 = 0.f, s1 = 0.f, s2 = 0.f, s3 = 0.f, s4 = 0.f;

#pragma unroll 1
    for (int tile = 0; tile < 2; ++tile) {
        if (tile) __syncthreads();              // protect LDS reuse across tiles
        Lcls[tid] = 0.f;
        __syncthreads();

        const size_t base4 = ((size_t)blockIdx.x * 2 + tile) * NCH;
        const float4* P = reinterpret_cast<const float4*>(pred) + base4;
        const float4* T = reinterpret_cast<const float4*>(targ) + base4;

        // coalesced loads: lane i -> consecutive 16B; 7.5 chunks/thread/tensor
#pragma unroll
        for (int k = 0; k < 8; ++k) {
            int idx = k * TPB + tid;
            if (idx < NCH) {                    // waves 2,3 skip k==7 (uniform)
                float4 pv = P[idx];
                float4 tv = T[idx];
                unsigned l    = 4u * (unsigned)idx;
                unsigned cell = l / 30u;
                unsigned e    = l - 30u * cell;  // even, 0..28
                float pc[4] = { pv.x, pv.y, pv.z, pv.w };
                float tc[4] = { tv.x, tv.y, tv.z, tv.w };
                float clsum = 0.f;
#pragma unroll
                for (int j = 0; j < 4; ++j) {
                    unsigned ej = e + j, c2 = cell;
                    if (ej >= 30u) { ej -= 30u; c2 += 1u; }   // only e==28, j>=2
                    if (ej < 10u) Lbox[c2 * 15u + ej] = pc[j];
                    if (ej < 5u)  Lbox[c2 * 15u + 10u + ej] = tc[j];
                    if (ej >= 10u) { float d = tc[j] - pc[j]; clsum += d * d; }
                }
                if (e >= 8u) atomicAdd(&Lcls[cell], clsum);   // class never wraps cells
            }
        }
        __syncthreads();

        // phase 2: one cell per thread from LDS (stride 15 odd -> conflict-free)
        {
            const float* Bx = &Lbox[tid * 15];
            float p0 = Bx[0], p1 = Bx[1], p2 = Bx[2], p3 = Bx[3], p4 = Bx[4];
            float p5 = Bx[5], p6 = Bx[6], p7 = Bx[7], p8 = Bx[8], p9 = Bx[9];
            float t0 = Bx[10], t1 = Bx[11], t2 = Bx[12], t3 = Bx[13], t4 = Bx[14];

            unsigned gcell = ((unsigned)blockIdx.x * 2u + (unsigned)tile) * CPT + (unsigned)tid;
            unsigned ij = gcell % 196u;
            float offx = (float)(ij % 14u);   // off = (j, i): x = column
            float offy = (float)(ij / 14u);

            float m;
            box_loss(p0, p1, p2, p3, p4, p5, p6, p7, p8, p9,
                     t0, t1, t2, t3, t4, offx, offy, s0, s1, s2, s3, m);
            s4 += m * Lcls[tid];
        }
    }

    // wave butterfly reduce
#pragma unroll
    for (int o = 32; o > 0; o >>= 1) {
        s0 += __shfl_down(s0, o);
        s1 += __shfl_down(s1, o);
        s2 += __shfl_down(s2, o);
        s3 += __shfl_down(s3, o);
        s4 += __shfl_down(s4, o);
    }

    __shared__ float red[4][5];
    int wave = tid >> 6;
    if ((tid & 63) == 0) {
        red[wave][0] = s0; red[wave][1] = s1; red[wave][2] = s2;
        red[wave][3] = s3; red[wave][4] = s4;
    }
    __syncthreads();
    if (tid == 0) {
        partA[blockIdx.x] = make_float4(
            red[0][0] + red[1][0] + red[2][0] + red[3][0],
            red[0][1] + red[1][1] + red[2][1] + red[3][1],
            red[0][2] + red[1][2] + red[2][2] + red[3][2],
            red[0][3] + red[1][3] + red[2][3] + red[3][3]);
        partB[blockIdx.x] =
            red[0][4] + red[1][4] + red[2][4] + red[3][4];
    }
}

__global__ __launch_bounds__(256) void yolo_final(
    const float4* __restrict__ partA, int nA,
    const float* __restrict__ partB,
    float* __restrict__ out, float invN)
{
    float a0 = 0.f, a1 = 0.f, a2 = 0.f, a3 = 0.f, b = 0.f;
    for (int i = threadIdx.x; i < nA; i += 256) {
        float4 v = partA[i];
        a0 += v.x; a1 += v.y; a2 += v.z; a3 += v.w;
        b += partB[i];
    }
#pragma unroll
    for (int o = 32; o > 0; o >>= 1) {
        a0 += __shfl_down(a0, o);
        a1 += __shfl_down(a1, o);
        a2 += __shfl_down(a2, o);
        a3 += __shfl_down(a3, o);
        b  += __shfl_down(b, o);
    }
    __shared__ float red[4][5];
    int wave = threadIdx.x >> 6;
    if ((threadIdx.x & 63) == 0) {
        red[wave][0] = a0; red[wave][1] = a1; red[wave][2] = a2;
        red[wave][3] = a3; red[wave][4] = b;
    }
    __syncthreads();
    if (threadIdx.x == 0) {
        float xy     = (red[0][0]+red[1][0]+red[2][0]+red[3][0]) * 5.0f * invN;
        float wh     = (red[0][1]+red[1][1]+red[2][1]+red[3][1]) * 5.0f * invN;
        float cobj   = (red[0][2]+red[1][2]+red[2][2]+red[3][2]) * invN;
        float cnoobj = (red[0][3]+red[1][3]+red[2][3]+red[3][3]) * 0.5f * invN;
        float cls    = (red[0][4]+red[1][4]+red[2][4]+red[3][4]) * invN;
        out[0] = xy + wh + cobj + cnoobj + cls;
        out[1] = xy;
        out[2] = wh;
        out[3] = cobj;
        out[4] = cnoobj;
        out[5] = cls;
    }
}

extern "C" void kernel_launch(void* const* d_in, const int* in_sizes, int n_in,
                              void* d_out, int out_size, void* d_ws, size_t ws_size,
                              hipStream_t stream)
{
    const float* pred = (const float*)d_in[0];
    const float* targ = (const float*)d_in[1];
    int ncells = in_sizes[0] / 30;             // 802816
    int blocks = ncells / (2 * CPT);           // 1568 exact (2 tiles per block)
    int N      = ncells / (SS * SS);

    float4* partA = (float4*)d_ws;
    float*  partB = (float*)((char*)d_ws + (size_t)blocks * sizeof(float4));

    yolo_fused<<<blocks, TPB, 0, stream>>>(pred, targ, partA, partB);
    yolo_final<<<1, 256, 0, stream>>>(partA, blocks, partB,
                                      (float*)d_out, 1.0f / (float)N);
}